// Round 6
// baseline (335.431 us; speedup 1.0000x reference)
//
#include <hip/hip_runtime.h>

#define T_TOTAL 4096
#define NT0     3072
#define CH      6144
#define TD_MAXL 1024

// ---- MFMA band-Gram parameters ----
#define KS     8            // K-split
#define KC     (CH / KS)    // 768 per block
#define BK     32           // K per LDS step
#define NSTEP  (KC / BK)    // 24
#define NTI    24           // I tiles (i < 3072)
#define ND     9            // diagonal tiles
#define NTILE  (NTI * ND)   // 216
#define NBLK   (NTILE * KS) // 1728
#define LDH    40           // LDS row stride in fp16 (32 data + 8 pad = 80 B, 16B-aligned)

typedef _Float16 half8  __attribute__((ext_vector_type(8)));
typedef float    f32x16 __attribute__((ext_vector_type(16)));

// d_ws layout: S f32[4096] @0 ; C f32[1024] @16384B ; PS f64[4097] @20480B

// S[t] = sum_ch x[t,ch]^2 (one block per t); fuses C-init for first 1024 blocks
__global__ __launch_bounds__(256) void s_kernel(const float* __restrict__ x,
                                                float* __restrict__ S,
                                                float* __restrict__ C) {
    const int t = blockIdx.x;
    if (t < TD_MAXL && threadIdx.x == 0) C[t] = 0.0f;
    const float4* row = (const float4*)(x + (size_t)t * CH);   // 1536 float4
    float s = 0.f;
    for (int k = threadIdx.x; k < CH / 4; k += 256) {
        float4 v = row[k];
        s = fmaf(v.x, v.x, s);
        s = fmaf(v.y, v.y, s);
        s = fmaf(v.z, v.z, s);
        s = fmaf(v.w, v.w, s);
    }
    #pragma unroll
    for (int off = 32; off >= 1; off >>= 1) s += __shfl_xor(s, off, 64);
    __shared__ float part[4];
    const int lane = threadIdx.x & 63, wid = threadIdx.x >> 6;
    if (lane == 0) part[wid] = s;
    __syncthreads();
    if (threadIdx.x == 0) S[t] = part[0] + part[1] + part[2] + part[3];
}

// single-block fp64 prefix scan: PS[k] = sum_{t<k} S[t], k in [0,4096]
__global__ __launch_bounds__(256) void scan_kernel(const float* __restrict__ S,
                                                   double* __restrict__ PS) {
    __shared__ double sh[256];
    const int tid = threadIdx.x;
    double run = 0.0;
    #pragma unroll
    for (int j = 0; j < 16; ++j) run += (double)S[16 * tid + j];
    sh[tid] = run;
    __syncthreads();
    for (int off = 1; off < 256; off <<= 1) {
        double tv = (tid >= off) ? sh[tid - off] : 0.0;
        __syncthreads();
        sh[tid] += tv;
        __syncthreads();
    }
    double base = (tid == 0) ? 0.0 : sh[tid - 1];
    if (tid == 0) PS[0] = 0.0;
    double r = base;
    #pragma unroll
    for (int j = 0; j < 16; ++j) {
        r += (double)S[16 * tid + j];
        PS[16 * tid + j + 1] = r;
    }
}

__device__ inline half8 pack8(const float4 u, const float4 v) {
    half8 h;
    h[0] = (_Float16)u.x; h[1] = (_Float16)u.y; h[2] = (_Float16)u.z; h[3] = (_Float16)u.w;
    h[4] = (_Float16)v.x; h[5] = (_Float16)v.y; h[6] = (_Float16)v.z; h[7] = (_Float16)v.w;
    return h;   // RNE scalar cvt (RTZ packed cvt would bias msd)
}

// Band Gram via 32x32x16 MFMA. Tile (I,D): G[i,j], i in [128I,+128), j in
// [128(I+D),+128). Wave (wm,wn) owns a 64x64 quadrant = 2x2 frags of 32x32.
// C_loc (256 f32) overlays As after the main loop -> LDS 40960 B = 4 blocks/CU.
__global__ __launch_bounds__(256, 2) void cross_mfma(const float* __restrict__ x,
                                                     float* __restrict__ C) {
    __shared__ _Float16 As[2][128][LDH];
    __shared__ _Float16 Bs[2][128][LDH];

    const int tid = threadIdx.x;
    const int bid = blockIdx.x;           // 0..1727
    const int xcd  = bid & 7;
    const int slot = bid >> 3;            // 0..215
    const int ks   = slot / 27;           // 0..7
    const int tt   = slot % 27;
    const int tile = xcd * 27 + tt;       // bijective, XCD-chunked
    const int I    = tile / ND;           // 0..23
    const int D    = tile % ND;           // 0..8
    const int i0 = I * 128, j0 = (I + D) * 128;
    const int k0 = ks * KC;

    // staging: 2 threads/row, 16 consecutive floats each
    const int srow = tid >> 1;            // 0..127
    const int skq  = (tid & 1) << 4;      // 0 or 16
    const float* gA = x + (size_t)(i0 + srow) * CH + k0 + skq;
    const float* gB = x + (size_t)(j0 + srow) * CH + k0 + skq;

    const int lane = tid & 63, wid = tid >> 6;
    const int wm = wid >> 1, wn = wid & 1;
    const int r32 = lane & 31, hi = lane >> 5;

    f32x16 acc[2][2];
    #pragma unroll
    for (int m = 0; m < 2; ++m)
        #pragma unroll
        for (int n = 0; n < 2; ++n) acc[m][n] = (f32x16)0.f;

    {   // prologue: stage step 0 into buffer 0
        float4 a[4], b[4];
        #pragma unroll
        for (int q = 0; q < 4; ++q) {
            a[q] = ((const float4*)gA)[q];
            b[q] = ((const float4*)gB)[q];
        }
        *(half8*)&As[0][srow][skq]     = pack8(a[0], a[1]);
        *(half8*)&As[0][srow][skq + 8] = pack8(a[2], a[3]);
        *(half8*)&Bs[0][srow][skq]     = pack8(b[0], b[1]);
        *(half8*)&Bs[0][srow][skq + 8] = pack8(b[2], b[3]);
    }

    int cur = 0;
    for (int t = 0; t < NSTEP; ++t) {
        float4 a[4], b[4];
        const bool more = (t + 1 < NSTEP);
        if (more) {   // issue next-step loads early (T14: latency under MFMA)
            const float* pA = gA + (size_t)(t + 1) * BK;
            const float* pB = gB + (size_t)(t + 1) * BK;
            #pragma unroll
            for (int q = 0; q < 4; ++q) {
                a[q] = ((const float4*)pA)[q];
                b[q] = ((const float4*)pB)[q];
            }
        }
        __syncthreads();   // prev writes to buf[cur] visible; prev reads drained

        half8 fA[2][2], fB[2][2];   // [frag][k-half]
        #pragma unroll
        for (int m = 0; m < 2; ++m)
            #pragma unroll
            for (int kk = 0; kk < 2; ++kk)
                fA[m][kk] = *(const half8*)&As[cur][wm * 64 + m * 32 + r32][kk * 16 + hi * 8];
        #pragma unroll
        for (int n = 0; n < 2; ++n)
            #pragma unroll
            for (int kk = 0; kk < 2; ++kk)
                fB[n][kk] = *(const half8*)&Bs[cur][wn * 64 + n * 32 + r32][kk * 16 + hi * 8];
        #pragma unroll
        for (int m = 0; m < 2; ++m)
            #pragma unroll
            for (int n = 0; n < 2; ++n) {
                acc[m][n] = __builtin_amdgcn_mfma_f32_32x32x16_f16(fA[m][0], fB[n][0],
                                                                   acc[m][n], 0, 0, 0);
                acc[m][n] = __builtin_amdgcn_mfma_f32_32x32x16_f16(fA[m][1], fB[n][1],
                                                                   acc[m][n], 0, 0, 0);
            }

        if (more) {
            const int nb = cur ^ 1;
            *(half8*)&As[nb][srow][skq]     = pack8(a[0], a[1]);
            *(half8*)&As[nb][srow][skq + 8] = pack8(a[2], a[3]);
            *(half8*)&Bs[nb][srow][skq]     = pack8(b[0], b[1]);
            *(half8*)&Bs[nb][srow][skq + 8] = pack8(b[2], b[3]);
        }
        cur ^= 1;
    }

    // epilogue: diagonal sums. C/D layout (m74/m101): col = lane&31,
    // row = (reg&3) + 8*(reg>>2) + 4*(lane>>5).
    // i_loc = 32fm + rr + 4hi ; j_loc = 32fn + r32
    // o = j_loc - i_loc = 32(fn-fm) - rr + (r32 - 4hi)
    __syncthreads();                       // all LDS frag reads done
    float* C_loc = (float*)&As[0][0][0];   // reuse As as 256-f32 reduction buf
    C_loc[tid] = 0.f;
    __syncthreads();

    const int base = 128 + 64 * (wn - wm) + (r32 - 4 * hi);
    f32x16 accD = acc[0][0] + acc[1][1];   // fn-fm == 0 pair, merged
    #pragma unroll
    for (int reg = 0; reg < 16; ++reg) {
        const int rr = (reg & 3) + 8 * (reg >> 2);
        atomicAdd(&C_loc[base - rr],      accD[reg]);
        atomicAdd(&C_loc[base + 32 - rr], acc[0][1][reg]);
        atomicAdd(&C_loc[base - 32 - rr], acc[1][0][reg]);
    }
    __syncthreads();

    const int td = D * 128 + tid - 128;    // masks D=0 lower triangle & td>=1024
    if (td >= 0 && td < TD_MAXL) atomicAdd(&C[td], C_loc[tid]);
}

// out[td] = (PS[td+3072] - PS[td] + PS[3072] - 2*C[td]) / (NT0*CH)
__global__ __launch_bounds__(256) void final_kernel(const double* __restrict__ PS,
                                                    const float* __restrict__ C,
                                                    float* __restrict__ out) {
    const int td = blockIdx.x * 256 + threadIdx.x;
    if (td >= TD_MAXL) return;
    const double P = PS[td + NT0] - PS[td];
    const double Q = PS[NT0];
    const double inv_M = 1.0 / ((double)NT0 * (double)CH);
    out[td] = (float)((P + Q - 2.0 * (double)C[td]) * inv_M);
}

extern "C" void kernel_launch(void* const* d_in, const int* in_sizes, int n_in,
                              void* d_out, int out_size, void* d_ws, size_t ws_size,
                              hipStream_t stream) {
    const float* x = (const float*)d_in[0];
    float* out = (float*)d_out;
    float*  S  = (float*)d_ws;                          // 4096 f32
    float*  C  = S + T_TOTAL;                           // 1024 f32
    double* PS = (double*)((char*)d_ws + 20480);        // 4097 f64

    s_kernel<<<dim3(T_TOTAL), dim3(256), 0, stream>>>(x, S, C);
    scan_kernel<<<dim3(1), dim3(256), 0, stream>>>(S, PS);
    cross_mfma<<<dim3(NBLK), dim3(256), 0, stream>>>(x, C);
    final_kernel<<<dim3(TD_MAXL / 256), dim3(256), 0, stream>>>(PS, C, out);
}

// Round 7
// 318.406 us; speedup vs baseline: 1.0535x; 1.0535x over previous
//
#include <hip/hip_runtime.h>

#define T_TOTAL 4096
#define NT0     3072
#define CH      6144
#define TD_MAXL 1024

// ---- MFMA band-Gram parameters ----
#define KS     4            // K-split
#define KC     (CH / KS)    // 1536 per block
#define BK     32           // K per LDS step (one 16x16x32 MFMA per frag)
#define NSTEP  (KC / BK)    // 48
#define NTI    24           // I tiles (i < 3072)
#define ND     9            // diagonal tiles
#define NTILE  (NTI * ND)   // 216
#define NBLK   (NTILE * KS) // 864
#define LDH    40           // LDS row stride in fp16 (32 data + 8 pad = 80 B, 16B-aligned)

typedef _Float16 half8 __attribute__((ext_vector_type(8)));
typedef float    f32x4 __attribute__((ext_vector_type(4)));

// d_ws layout: S f32[4096] @0 ; C f32[1024] @16384B

// S[t] = sum_ch x[t,ch]^2 (one block per t); fuses C-init for first 1024 blocks
__global__ __launch_bounds__(256) void s_kernel(const float* __restrict__ x,
                                                float* __restrict__ S,
                                                float* __restrict__ C) {
    const int t = blockIdx.x;
    if (t < TD_MAXL && threadIdx.x == 0) C[t] = 0.0f;
    const float4* row = (const float4*)(x + (size_t)t * CH);   // 1536 float4
    float s = 0.f;
    for (int k = threadIdx.x; k < CH / 4; k += 256) {
        float4 v = row[k];
        s = fmaf(v.x, v.x, s);
        s = fmaf(v.y, v.y, s);
        s = fmaf(v.z, v.z, s);
        s = fmaf(v.w, v.w, s);
    }
    #pragma unroll
    for (int off = 32; off >= 1; off >>= 1) s += __shfl_xor(s, off, 64);
    __shared__ float part[4];
    const int lane = threadIdx.x & 63, wid = threadIdx.x >> 6;
    if (lane == 0) part[wid] = s;
    __syncthreads();
    if (threadIdx.x == 0) S[t] = part[0] + part[1] + part[2] + part[3];
}

__device__ inline half8 pack8(const float4 u, const float4 v) {
    half8 h;
    h[0] = (_Float16)u.x; h[1] = (_Float16)u.y; h[2] = (_Float16)u.z; h[3] = (_Float16)u.w;
    h[4] = (_Float16)v.x; h[5] = (_Float16)v.y; h[6] = (_Float16)v.z; h[7] = (_Float16)v.w;
    return h;   // RNE scalar cvt (RTZ packed cvt would bias msd)
}

// Band Gram via 16x16x32 MFMA. Tile (I,D): G[i,j], i in [128I,+128),
// j in [128(I+D),+128); diagonal sums j-i=td accumulated into C[td].
// 4 waves, each a 64x64 quadrant = 4x4 fragments.
// KEY CHANGE vs R5/R6: next-step global loads are issued AFTER the barrier,
// so their vmcnt wait lands after the ds_read+MFMA phase (real overlap) —
// previously they were issued right before __syncthreads, whose implicit
// vmcnt(0) drain serialized every step (latency-bound: MfmaUtil 8-12%).
__global__ __launch_bounds__(256, 2) void cross_mfma(const float* __restrict__ x,
                                                     float* __restrict__ C) {
    __shared__ _Float16 As[2][128][LDH];
    __shared__ _Float16 Bs[2][128][LDH];
    __shared__ float    C_loc[256];

    const int tid = threadIdx.x;
    const int bid = blockIdx.x;           // 0..863
    const int xcd  = bid & 7;
    const int slot = bid >> 3;            // 0..107
    const int ks   = slot / 27;           // 0..3
    const int tt   = slot % 27;
    const int tile = xcd * 27 + tt;       // 0..215, bijective, XCD-chunked
    const int I    = tile / ND;           // 0..23
    const int D    = tile % ND;           // 0..8
    const int i0 = I * 128, j0 = (I + D) * 128;
    const int k0 = ks * KC;

    C_loc[tid] = 0.f;                     // visible by first __syncthreads

    // staging: 2 threads/row, 16 consecutive floats each (4x float4)
    const int srow = tid >> 1;            // 0..127
    const int skq  = (tid & 1) << 4;      // 0 or 16
    const float* gA = x + (size_t)(i0 + srow) * CH + k0 + skq;
    const float* gB = x + (size_t)(j0 + srow) * CH + k0 + skq;

    const int lane = tid & 63, wid = tid >> 6;
    const int wm = wid >> 1, wn = wid & 1;       // 2x2 waves of 64x64
    const int fr = lane & 15, ss = lane >> 4;    // frag row + k-slot
    const int rowA = wm * 64 + fr;
    const int rowB = wn * 64 + fr;

    f32x4 acc[4][4];
    #pragma unroll
    for (int m = 0; m < 4; ++m)
        #pragma unroll
        for (int n = 0; n < 4; ++n) acc[m][n] = (f32x4)0.f;

    {   // prologue: stage step 0 into buffer 0 (latency exposed once)
        float4 a[4], b[4];
        #pragma unroll
        for (int q = 0; q < 4; ++q) {
            a[q] = ((const float4*)gA)[q];
            b[q] = ((const float4*)gB)[q];
        }
        *(half8*)&As[0][srow][skq]     = pack8(a[0], a[1]);
        *(half8*)&As[0][srow][skq + 8] = pack8(a[2], a[3]);
        *(half8*)&Bs[0][srow][skq]     = pack8(b[0], b[1]);
        *(half8*)&Bs[0][srow][skq + 8] = pack8(b[2], b[3]);
    }

    int cur = 0;
    for (int t = 0; t < NSTEP; ++t) {
        __syncthreads();   // buf[cur] writes visible; buf[cur^1] readers drained

        // issue next-step loads NOW — vmcnt wait sits after ds_reads + MFMAs
        float4 a[4], b[4];
        const bool more = (t + 1 < NSTEP);
        if (more) {
            const float* pA = gA + (size_t)(t + 1) * BK;
            const float* pB = gB + (size_t)(t + 1) * BK;
            #pragma unroll
            for (int q = 0; q < 4; ++q) {
                a[q] = ((const float4*)pA)[q];
                b[q] = ((const float4*)pB)[q];
            }
        }

        half8 fA[4], fB[4];
        #pragma unroll
        for (int m = 0; m < 4; ++m)
            fA[m] = *(const half8*)&As[cur][rowA + 16 * m][ss * 8];
        #pragma unroll
        for (int n = 0; n < 4; ++n)
            fB[n] = *(const half8*)&Bs[cur][rowB + 16 * n][ss * 8];
        #pragma unroll
        for (int m = 0; m < 4; ++m)
            #pragma unroll
            for (int n = 0; n < 4; ++n)
                acc[m][n] = __builtin_amdgcn_mfma_f32_16x16x32_f16(fA[m], fB[n],
                                                                   acc[m][n], 0, 0, 0);
        if (more) {
            const int nb = cur ^ 1;
            *(half8*)&As[nb][srow][skq]     = pack8(a[0], a[1]);
            *(half8*)&As[nb][srow][skq + 8] = pack8(a[2], a[3]);
            *(half8*)&Bs[nb][srow][skq]     = pack8(b[0], b[1]);
            *(half8*)&Bs[nb][srow][skq + 8] = pack8(b[2], b[3]);
        }
        cur ^= 1;
    }

    // epilogue: diagonal sums. i_loc = 64wm+16m+4ss+rr, j_loc = 64wn+16n+fr
    // o = j_loc - i_loc = 64(wn-wm) + 16(n-m) + (fr-4ss) - rr, in (-128,128)
    float buck[7][4];
    #pragma unroll
    for (int dd = 0; dd < 7; ++dd)
        #pragma unroll
        for (int rr = 0; rr < 4; ++rr) buck[dd][rr] = 0.f;
    #pragma unroll
    for (int m = 0; m < 4; ++m)
        #pragma unroll
        for (int n = 0; n < 4; ++n)
            #pragma unroll
            for (int rr = 0; rr < 4; ++rr)
                buck[n - m + 3][rr] += acc[m][n][rr];

    const int obase = 64 * (wn - wm) + 128 + (fr - (ss << 2));
    #pragma unroll
    for (int dd = 0; dd < 7; ++dd)
        #pragma unroll
        for (int rr = 0; rr < 4; ++rr)
            atomicAdd(&C_loc[obase + 16 * (dd - 3) - rr], buck[dd][rr]);
    __syncthreads();

    const int td = D * 128 + tid - 128;   // masks D=0 lower triangle & td>=1024
    if (td >= 0 && td < TD_MAXL) atomicAdd(&C[td], C_loc[tid]);
}

// msd[td] = (P[td] + Q - 2*C[td]) / (NT0*CH) — one block per td, tree reduce
__global__ __launch_bounds__(256) void combine_kernel(const float* __restrict__ S,
                                                      const float* __restrict__ C,
                                                      float* __restrict__ out) {
    const int td = blockIdx.x;
    float p = 0.f, q = 0.f;
    for (int t = threadIdx.x; t < NT0; t += 256) {
        p += S[t + td];
        q += S[t];
    }
    #pragma unroll
    for (int off = 32; off >= 1; off >>= 1) {
        p += __shfl_xor(p, off, 64);
        q += __shfl_xor(q, off, 64);
    }
    __shared__ float pp[4], qq[4];
    const int lane = threadIdx.x & 63, wid = threadIdx.x >> 6;
    if (lane == 0) { pp[wid] = p; qq[wid] = q; }
    __syncthreads();
    if (threadIdx.x == 0) {
        const float P = pp[0] + pp[1] + pp[2] + pp[3];
        const float Q = qq[0] + qq[1] + qq[2] + qq[3];
        const float inv_M = 1.0f / ((float)NT0 * (float)CH);
        out[td] = (P + Q - 2.0f * C[td]) * inv_M;
    }
}

extern "C" void kernel_launch(void* const* d_in, const int* in_sizes, int n_in,
                              void* d_out, int out_size, void* d_ws, size_t ws_size,
                              hipStream_t stream) {
    const float* x = (const float*)d_in[0];
    float* out = (float*)d_out;
    float* S = (float*)d_ws;            // 4096 f32
    float* C = S + T_TOTAL;             // 1024 f32

    s_kernel<<<dim3(T_TOTAL), dim3(256), 0, stream>>>(x, S, C);
    cross_mfma<<<dim3(NBLK), dim3(256), 0, stream>>>(x, C);
    combine_kernel<<<dim3(TD_MAXL), dim3(256), 0, stream>>>(S, C, out);
}

// Round 8
// 261.097 us; speedup vs baseline: 1.2847x; 1.2195x over previous
//
#include <hip/hip_runtime.h>
#include <stdint.h>

#define T_TOTAL 4096
#define NT0     3072
#define CH      6144
#define TD_MAXL 1024

// ---- MFMA band-Gram parameters ----
#define KS     4            // K-split
#define KC     (CH / KS)    // 1536 halfs per block
#define BK     32           // K per LDS step (one 16x16x32 MFMA per frag)
#define NSTEP  (KC / BK)    // 48
#define NTI    24           // I tiles (i < 3072)
#define ND     9            // diagonal tiles
#define NTILE  (NTI * ND)   // 216
#define NBLK   (NTILE * KS) // 864  (<= 1024 resident at 4 blocks/CU: single generation)
#define LDHF   40           // fallback-path LDS stride (halfs)

typedef _Float16 half8 __attribute__((ext_vector_type(8)));
typedef float    f32x4 __attribute__((ext_vector_type(4)));

// d_ws layout: S f32[4096] @0 ; C f32[1024] @16384 ; xh fp16[4096*6144] @32768

__device__ inline void gload16(const void* g, void* l) {
    __builtin_amdgcn_global_load_lds(
        (const __attribute__((address_space(1))) unsigned int*)g,
        (__attribute__((address_space(3))) unsigned int*)l, 16, 0, 0);
}

// S[t] = sum_ch x[t,ch]^2 (one block per t); fuses C-init
__global__ __launch_bounds__(256) void s_kernel(const float* __restrict__ x,
                                                float* __restrict__ S,
                                                float* __restrict__ C) {
    const int t = blockIdx.x;
    if (t < TD_MAXL && threadIdx.x == 0) C[t] = 0.0f;
    const float4* row = (const float4*)(x + (size_t)t * CH);
    float s = 0.f;
    for (int k = threadIdx.x; k < CH / 4; k += 256) {
        float4 v = row[k];
        s = fmaf(v.x, v.x, s); s = fmaf(v.y, v.y, s);
        s = fmaf(v.z, v.z, s); s = fmaf(v.w, v.w, s);
    }
    #pragma unroll
    for (int off = 32; off >= 1; off >>= 1) s += __shfl_xor(s, off, 64);
    __shared__ float part[4];
    const int lane = threadIdx.x & 63, wid = threadIdx.x >> 6;
    if (lane == 0) part[wid] = s;
    __syncthreads();
    if (threadIdx.x == 0) S[t] = part[0] + part[1] + part[2] + part[3];
}

__device__ inline half8 pack8(const float4 u, const float4 v) {
    half8 h;
    h[0] = (_Float16)u.x; h[1] = (_Float16)u.y; h[2] = (_Float16)u.z; h[3] = (_Float16)u.w;
    h[4] = (_Float16)v.x; h[5] = (_Float16)v.y; h[6] = (_Float16)v.z; h[7] = (_Float16)v.w;
    return h;   // RNE scalar cvt
}

// x (fp32) -> xh (fp16), 8 elems/thread, exact grid 12288x256
__global__ __launch_bounds__(256) void cvt_kernel(const float* __restrict__ x,
                                                  _Float16* __restrict__ xh) {
    const size_t total = (size_t)T_TOTAL * CH;
    size_t i = ((size_t)blockIdx.x * 256 + threadIdx.x) * 8;
    const size_t stride = (size_t)gridDim.x * 256 * 8;
    for (; i < total; i += stride) {
        float4 u = *(const float4*)(x + i);
        float4 v = *(const float4*)(x + i + 4);
        *(half8*)(xh + i) = pack8(u, v);
    }
}

// Band Gram via 16x16x32 MFMA on pre-converted fp16, staged with
// global_load_lds (direct DMA, no cvt / no ds_write / no reg roundtrip).
// LDS is LINEAR [128][32] halfs (64 B rows); bank-conflict fix is the
// both-sides swizzle (rule #21): physical 16B-slot p = ss ^ (row&3),
// realized by pre-swizzling the per-lane GLOBAL source column and reading
// with the same XOR (compile-time per lane, since row%4 == fr%4 for all m).
__global__ __launch_bounds__(256, 4) void cross_mfma(const _Float16* __restrict__ xh,
                                                     float* __restrict__ C) {
    __shared__ _Float16 As[2][128][BK];   // 16 KB
    __shared__ _Float16 Bs[2][128][BK];   // 16 KB
    __shared__ float    C_loc[256];

    const int tid = threadIdx.x;
    const int bid = blockIdx.x;           // 0..863
    const int xcd  = bid & 7;
    const int slot = bid >> 3;
    const int ks   = slot / 27;
    const int tt   = slot % 27;
    const int tile = xcd * 27 + tt;       // bijective, XCD-chunked
    const int I    = tile / ND;
    const int D    = tile % ND;
    const int i0 = I * 128, j0 = (I + D) * 128;
    const int k0 = ks * KC;

    C_loc[tid] = 0.f;

    const int lane = tid & 63, wid = tid >> 6;

    // ---- DMA source pointers (per-lane, pre-swizzled column) ----
    // wave w stages rows [w*32, w*32+32) of both panels, 2 chunks of 16 rows.
    // HW writes lane l -> lds_base + l*16: row = chunk + (l>>2), slot = l&3.
    const int rsub  = lane >> 2;              // row within 16-row chunk
    const int pslot = lane & 3;               // physical slot this lane fills
    const int swz   = ((pslot ^ (rsub & 3)) << 3);   // swizzled col (halfs)
    const int c0row = wid * 32;
    const _Float16* sA0 = xh + (size_t)(i0 + c0row + rsub) * CH + k0 + swz;
    const _Float16* sB0 = xh + (size_t)(j0 + c0row + rsub) * CH + k0 + swz;

#define STAGE(buf, toff) { \
        const size_t ko = (size_t)(toff) * BK; \
        gload16(sA0 + ko,            &As[buf][c0row][0]);      \
        gload16(sA0 + 16 * CH + ko,  &As[buf][c0row + 16][0]); \
        gload16(sB0 + ko,            &Bs[buf][c0row][0]);      \
        gload16(sB0 + 16 * CH + ko,  &Bs[buf][c0row + 16][0]); \
    }

    // ---- fragment read addressing (compile-time swizzle per lane) ----
    const int wm = wid >> 1, wn = wid & 1;
    const int fr = lane & 15, ss = lane >> 4;
    const int rdslot = ((ss ^ (fr & 3)) << 4);            // byte offset of slot
    const int offA = (wm * 64 + fr) * 64 + rdslot;        // + m*1024 per frag
    const int offB = (wn * 64 + fr) * 64 + rdslot;

    f32x4 acc[4][4];
    #pragma unroll
    for (int m = 0; m < 4; ++m)
        #pragma unroll
        for (int n = 0; n < 4; ++n) acc[m][n] = (f32x4)0.f;

    STAGE(0, 0);
    __syncthreads();    // vmcnt drain: buffer 0 ready

    int cur = 0;
    for (int t = 0; t < NSTEP; ++t) {
        if (t + 1 < NSTEP) STAGE(cur ^ 1, t + 1);   // DMA covered by this step

        const char* bA = (const char*)&As[cur][0][0];
        const char* bB = (const char*)&Bs[cur][0][0];
        half8 fA[4], fB[4];
        #pragma unroll
        for (int m = 0; m < 4; ++m)
            fA[m] = *(const half8*)(bA + offA + m * (16 * BK * 2));
        #pragma unroll
        for (int n = 0; n < 4; ++n)
            fB[n] = *(const half8*)(bB + offB + n * (16 * BK * 2));
        #pragma unroll
        for (int m = 0; m < 4; ++m)
            #pragma unroll
            for (int n = 0; n < 4; ++n)
                acc[m][n] = __builtin_amdgcn_mfma_f32_16x16x32_f16(fA[m], fB[n],
                                                                   acc[m][n], 0, 0, 0);
        __syncthreads();   // reads done + next DMA landed
        cur ^= 1;
    }
#undef STAGE

    // epilogue: diagonal sums. i_loc = 64wm+16m+4ss+rr, j_loc = 64wn+16n+fr
    // o = 64(wn-wm) + 16(n-m) + (fr-4ss) - rr  (verified: R7 absmax 0.0)
    float buck[7][4];
    #pragma unroll
    for (int dd = 0; dd < 7; ++dd)
        #pragma unroll
        for (int rr = 0; rr < 4; ++rr) buck[dd][rr] = 0.f;
    #pragma unroll
    for (int m = 0; m < 4; ++m)
        #pragma unroll
        for (int n = 0; n < 4; ++n)
            #pragma unroll
            for (int rr = 0; rr < 4; ++rr)
                buck[n - m + 3][rr] += acc[m][n][rr];

    const int obase = 64 * (wn - wm) + 128 + (fr - (ss << 2));
    #pragma unroll
    for (int dd = 0; dd < 7; ++dd)
        #pragma unroll
        for (int rr = 0; rr < 4; ++rr)
            atomicAdd(&C_loc[obase + 16 * (dd - 3) - rr], buck[dd][rr]);
    __syncthreads();

    const int td = D * 128 + tid - 128;
    if (td >= 0 && td < TD_MAXL) atomicAdd(&C[td], C_loc[tid]);
}

// ---- fallback (R7-verified) if ws can't hold xh ----
__global__ __launch_bounds__(256, 2) void cross_fallback(const float* __restrict__ x,
                                                         float* __restrict__ C) {
    __shared__ _Float16 As[2][128][LDHF];
    __shared__ _Float16 Bs[2][128][LDHF];
    __shared__ float    C_loc[256];
    const int tid = threadIdx.x;
    const int bid = blockIdx.x;
    const int xcd  = bid & 7;
    const int slot = bid >> 3;
    const int ks   = slot / 27;
    const int tt   = slot % 27;
    const int tile = xcd * 27 + tt;
    const int I    = tile / ND;
    const int D    = tile % ND;
    const int i0 = I * 128, j0 = (I + D) * 128;
    const int k0 = ks * KC;
    C_loc[tid] = 0.f;
    const int srow = tid >> 1, skq = (tid & 1) << 4;
    const float* gA = x + (size_t)(i0 + srow) * CH + k0 + skq;
    const float* gB = x + (size_t)(j0 + srow) * CH + k0 + skq;
    const int lane = tid & 63, wid = tid >> 6;
    const int wm = wid >> 1, wn = wid & 1;
    const int fr = lane & 15, ss = lane >> 4;
    const int rowA = wm * 64 + fr, rowB = wn * 64 + fr;
    f32x4 acc[4][4];
    #pragma unroll
    for (int m = 0; m < 4; ++m)
        #pragma unroll
        for (int n = 0; n < 4; ++n) acc[m][n] = (f32x4)0.f;
    {
        float4 a[4], b[4];
        #pragma unroll
        for (int q = 0; q < 4; ++q) { a[q] = ((const float4*)gA)[q]; b[q] = ((const float4*)gB)[q]; }
        *(half8*)&As[0][srow][skq]     = pack8(a[0], a[1]);
        *(half8*)&As[0][srow][skq + 8] = pack8(a[2], a[3]);
        *(half8*)&Bs[0][srow][skq]     = pack8(b[0], b[1]);
        *(half8*)&Bs[0][srow][skq + 8] = pack8(b[2], b[3]);
    }
    int cur = 0;
    for (int t = 0; t < NSTEP; ++t) {
        __syncthreads();
        float4 a[4], b[4];
        const bool more = (t + 1 < NSTEP);
        if (more) {
            const float* pA = gA + (size_t)(t + 1) * BK;
            const float* pB = gB + (size_t)(t + 1) * BK;
            #pragma unroll
            for (int q = 0; q < 4; ++q) { a[q] = ((const float4*)pA)[q]; b[q] = ((const float4*)pB)[q]; }
        }
        half8 fA[4], fB[4];
        #pragma unroll
        for (int m = 0; m < 4; ++m) fA[m] = *(const half8*)&As[cur][rowA + 16 * m][ss * 8];
        #pragma unroll
        for (int n = 0; n < 4; ++n) fB[n] = *(const half8*)&Bs[cur][rowB + 16 * n][ss * 8];
        #pragma unroll
        for (int m = 0; m < 4; ++m)
            #pragma unroll
            for (int n = 0; n < 4; ++n)
                acc[m][n] = __builtin_amdgcn_mfma_f32_16x16x32_f16(fA[m], fB[n], acc[m][n], 0, 0, 0);
        if (more) {
            const int nb = cur ^ 1;
            *(half8*)&As[nb][srow][skq]     = pack8(a[0], a[1]);
            *(half8*)&As[nb][srow][skq + 8] = pack8(a[2], a[3]);
            *(half8*)&Bs[nb][srow][skq]     = pack8(b[0], b[1]);
            *(half8*)&Bs[nb][srow][skq + 8] = pack8(b[2], b[3]);
        }
        cur ^= 1;
    }
    float buck[7][4];
    #pragma unroll
    for (int dd = 0; dd < 7; ++dd)
        #pragma unroll
        for (int rr = 0; rr < 4; ++rr) buck[dd][rr] = 0.f;
    #pragma unroll
    for (int m = 0; m < 4; ++m)
        #pragma unroll
        for (int n = 0; n < 4; ++n)
            #pragma unroll
            for (int rr = 0; rr < 4; ++rr)
                buck[n - m + 3][rr] += acc[m][n][rr];
    const int obase = 64 * (wn - wm) + 128 + (fr - (ss << 2));
    #pragma unroll
    for (int dd = 0; dd < 7; ++dd)
        #pragma unroll
        for (int rr = 0; rr < 4; ++rr)
            atomicAdd(&C_loc[obase + 16 * (dd - 3) - rr], buck[dd][rr]);
    __syncthreads();
    const int td = D * 128 + tid - 128;
    if (td >= 0 && td < TD_MAXL) atomicAdd(&C[td], C_loc[tid]);
}

// msd[td] = (P[td] + Q - 2*C[td]) / (NT0*CH) — one block per td
__global__ __launch_bounds__(256) void combine_kernel(const float* __restrict__ S,
                                                      const float* __restrict__ C,
                                                      float* __restrict__ out) {
    const int td = blockIdx.x;
    float p = 0.f, q = 0.f;
    for (int t = threadIdx.x; t < NT0; t += 256) {
        p += S[t + td];
        q += S[t];
    }
    #pragma unroll
    for (int off = 32; off >= 1; off >>= 1) {
        p += __shfl_xor(p, off, 64);
        q += __shfl_xor(q, off, 64);
    }
    __shared__ float pp[4], qq[4];
    const int lane = threadIdx.x & 63, wid = threadIdx.x >> 6;
    if (lane == 0) { pp[wid] = p; qq[wid] = q; }
    __syncthreads();
    if (threadIdx.x == 0) {
        const float P = pp[0] + pp[1] + pp[2] + pp[3];
        const float Q = qq[0] + qq[1] + qq[2] + qq[3];
        const float inv_M = 1.0f / ((float)NT0 * (float)CH);
        out[td] = (P + Q - 2.0f * C[td]) * inv_M;
    }
}

extern "C" void kernel_launch(void* const* d_in, const int* in_sizes, int n_in,
                              void* d_out, int out_size, void* d_ws, size_t ws_size,
                              hipStream_t stream) {
    const float* x = (const float*)d_in[0];
    float* out = (float*)d_out;
    float* S = (float*)d_ws;                               // 4096 f32
    float* C = (float*)((char*)d_ws + 16384);              // 1024 f32
    _Float16* xh = (_Float16*)((char*)d_ws + 32768);       // 50.3 MB fp16 copy
    const size_t need = 32768 + (size_t)T_TOTAL * CH * sizeof(_Float16);

    s_kernel<<<dim3(T_TOTAL), dim3(256), 0, stream>>>(x, S, C);
    if (ws_size >= need) {
        cvt_kernel<<<dim3(12288), dim3(256), 0, stream>>>(x, xh);
        cross_mfma<<<dim3(NBLK), dim3(256), 0, stream>>>(xh, C);
    } else {
        cross_fallback<<<dim3(NBLK), dim3(256), 0, stream>>>(x, C);
    }
    combine_kernel<<<dim3(TD_MAXL), dim3(256), 0, stream>>>(S, C, out);
}